// Round 9
// baseline (141.437 us; speedup 1.0000x reference)
//
#include <hip/hip_runtime.h>
#include <cstdint>

// B=16384 rows, K=2048 centers, D=128, T=1.0
// Outputs (flat, f32): out[B*D], center[K*D], label[B]
#define NB 16384
#define NK 2048
#define ND 128
#define MARGIN 0.10f
#define CAP 2048

typedef __attribute__((ext_vector_type(8))) short bf16x8;
typedef __attribute__((ext_vector_type(4))) float f32x4;
typedef unsigned long long u64;

__device__ __forceinline__ unsigned short f2bf(float f) {
    unsigned u = __float_as_uint(f);
    u += 0x7fffu + ((u >> 16) & 1u);          // round-to-nearest-even
    return (unsigned short)(u >> 16);
}

// Exact refine, R1-identical fp32 chain (serial fmaf dot, t=x2+c2,
// fmaf(-2,dot,t), max, sqrt; u64 key -> lowest k on tie).
__device__ __forceinline__ void refine_one(const float* __restrict__ x,
                                           const float* __restrict__ center,
                                           const float* __restrict__ c2,
                                           const float* __restrict__ x2g,
                                           u64* __restrict__ partial,
                                           int row, int col) {
    const float* xr = x + (long)row * ND;
    const float* cr = center + (long)col * ND;
    float dot = 0.f;
#pragma unroll 8
    for (int d = 0; d < ND; ++d) dot = fmaf(xr[d], cr[d], dot);
    float t = x2g[row] + c2[col];
    float f = fmaxf(fmaf(-2.0f, dot, t), 0.0f);
    float s = __builtin_sqrtf(f);
    u64 key = ((u64)__float_as_uint(s) << 32) | (unsigned)col;
    atomicMin(&partial[row], key);
}

// ---------------------------------------------------------------------------
// Prep (5512 blocks) — R7-validated layout:
//  [0,4096)    x2 (R1-identical butterfly) + partial init
//  [4096,5120) xbf: x -> bf16 MFMA A-frag layout (R4-validated)
//  [5120,5248) cbf: center -> bf16 MFMA B-frag layout (R4-validated)
//  [5248,5256) c2 (R1-identical chain)
//  [5256,5512) center passthrough copy
// ---------------------------------------------------------------------------
__global__ __launch_bounds__(256)
void prep(const float* __restrict__ x,
          const float* __restrict__ c,
          unsigned short* __restrict__ xbf,
          unsigned short* __restrict__ cbf,
          float* __restrict__ c2,
          float* __restrict__ x2,
          u64* __restrict__ partial,
          float* __restrict__ out_center) {
    const int bid = blockIdx.x;
    const int tid = threadIdx.x;
    if (bid < 4096) {
        const int row  = bid * 4 + (tid >> 6);
        const int lane = tid & 63;
        float2 v = ((const float2*)(x + (long)row * ND))[lane];
        float s = v.x * v.x + v.y * v.y;
#pragma unroll
        for (int off = 32; off; off >>= 1) s += __shfl_xor(s, off, 64);
        if (lane == 0) {
            x2[row] = s;
            partial[row] = ~0ULL;
        }
    } else if (bid < 5120) {
        int t = (bid - 4096) * 256 + tid;     // 0..262143
        int lane = t & 63, s = (t >> 6) & 3, rt = t >> 8;
        int row = rt * 16 + (lane & 15);
        int d0  = s * 32 + (lane >> 4) * 8;
        const float* src = x + (long)row * ND + d0;
        unsigned short h[8];
#pragma unroll
        for (int j = 0; j < 8; ++j) h[j] = f2bf(src[j]);
        int4 pk;
        pk.x = h[0] | (h[1] << 16); pk.y = h[2] | (h[3] << 16);
        pk.z = h[4] | (h[5] << 16); pk.w = h[6] | (h[7] << 16);
        ((int4*)xbf)[t] = pk;
    } else if (bid < 5248) {
        int t = (bid - 5120) * 256 + tid;     // 0..32767
        int lane = t & 63, s = (t >> 6) & 3, kt = t >> 8;
        int kc = kt * 16 + (lane & 15);
        int d0 = s * 32 + (lane >> 4) * 8;
        const float* src = c + (long)kc * ND + d0;
        unsigned short h[8];
#pragma unroll
        for (int j = 0; j < 8; ++j) h[j] = f2bf(src[j]);
        int4 pk;
        pk.x = h[0] | (h[1] << 16); pk.y = h[2] | (h[3] << 16);
        pk.z = h[4] | (h[5] << 16); pk.w = h[6] | (h[7] << 16);
        ((int4*)cbf)[t] = pk;
    } else if (bid < 5256) {
        int k = (bid - 5248) * 256 + tid;
        const float4* row = (const float4*)(c + (long)k * ND);
        float s = 0.f;
#pragma unroll 8
        for (int i = 0; i < ND / 4; ++i) {
            float4 v = row[i];
            s += v.x * v.x + v.y * v.y + v.z * v.z + v.w * v.w;
        }
        c2[k] = s;
    } else {
        int i = (bid - 5256) * 256 + tid;
        ((float4*)out_center)[i] = ((const float4*)c)[i];
    }
}

// ---------------------------------------------------------------------------
// Main: 2048 blocks (rg 0..511 x ks 0..3) x 256 threads. Block = 32 rows x
// 512 k; wave = 2 row-tiles x 8 k-tiles, ONE sweep, acc[2][8] live.
// NO LDS staging / NO per-block x2 / NO A-conversion: A-frags and scalars
// come straight from prep outputs in global (all loads independent).
// Block-min + MARGIN threshold (superset of true winner per k-subset),
// collect from live accs, exact refine (R1 chain), global u64 atomicMin.
// ---------------------------------------------------------------------------
__global__ __launch_bounds__(256)
void kmeans_main(const unsigned short* __restrict__ xbf,
                 const unsigned short* __restrict__ cbf,
                 const float* __restrict__ c2,
                 const float* __restrict__ x2g,
                 const float* __restrict__ x,
                 const float* __restrict__ center,
                 u64* __restrict__ partial) {
    __shared__ unsigned bmin[32];
    __shared__ unsigned buf[CAP];              // 8 KB candidates
    __shared__ unsigned cnt;

    const int tid  = threadIdx.x;
    const int lane = tid & 63;
    const int wave = __builtin_amdgcn_readfirstlane(tid >> 6);  // 0..3
    const int rg = blockIdx.x >> 2;            // row-group (32 rows)
    const int ks = blockIdx.x & 3;             // k-split (512 k)
    const long rb = (long)rg * 32;

    if (tid < 32) bmin[tid] = 0x7f800000u;
    if (tid == 0) cnt = 0;
    __syncthreads();                           // init visible before LDS atomics

    // ---- A-frags direct from xbf (2 row-tiles, 8 x b128, independent) ----
    const bf16x8* XF = (const bf16x8*)xbf;
    bf16x8 af[2][4];
#pragma unroll
    for (int rt = 0; rt < 2; ++rt)
#pragma unroll
        for (int s = 0; s < 4; ++s)
            af[rt][s] = XF[((rg * 2 + rt) * 4 + s) * 64 + lane];

    float x2p[2][4];
#pragma unroll
    for (int rt = 0; rt < 2; ++rt)
#pragma unroll
        for (int reg = 0; reg < 4; ++reg)
            x2p[rt][reg] = x2g[rb + rt * 16 + (lane >> 4) * 4 + reg];

    // ---- one sweep: 8 k-tiles, acc kept live ----
    const bf16x8* CF = (const bf16x8*)cbf;
    const int kt0 = ks * 32 + wave * 8;        // wave's first 16-k tile

    f32x4 acc[2][8];
#pragma unroll
    for (int rt = 0; rt < 2; ++rt)
#pragma unroll
        for (int ct = 0; ct < 8; ++ct) acc[rt][ct] = (f32x4){0.f, 0.f, 0.f, 0.f};

#pragma unroll
    for (int ct = 0; ct < 8; ++ct) {
        const int kt = kt0 + ct;
#pragma unroll
        for (int s = 0; s < 4; ++s) {
            bf16x8 b = CF[(kt * 4 + s) * 64 + lane];
            acc[0][ct] = __builtin_amdgcn_mfma_f32_16x16x32_bf16(af[0][s], b, acc[0][ct], 0, 0, 0);
            acc[1][ct] = __builtin_amdgcn_mfma_f32_16x16x32_bf16(af[1][s], b, acc[1][ct], 0, 0, 0);
        }
    }

    float c2v[8];
#pragma unroll
    for (int ct = 0; ct < 8; ++ct)
        c2v[ct] = c2[(kt0 + ct) * 16 + (lane & 15)];

    // ---- block-min per row (clamped >=0 so uint order works) ----
    float rmin[2][4];
#pragma unroll
    for (int rt = 0; rt < 2; ++rt)
#pragma unroll
        for (int reg = 0; reg < 4; ++reg) rmin[rt][reg] = __builtin_inff();
#pragma unroll
    for (int rt = 0; rt < 2; ++rt)
#pragma unroll
        for (int ct = 0; ct < 8; ++ct)
#pragma unroll
            for (int reg = 0; reg < 4; ++reg) {
                float d2 = fmaf(-2.f, acc[rt][ct][reg], x2p[rt][reg] + c2v[ct]);
                rmin[rt][reg] = fminf(rmin[rt][reg], d2);
            }
#pragma unroll
    for (int rt = 0; rt < 2; ++rt)
#pragma unroll
        for (int reg = 0; reg < 4; ++reg) {
            float v = rmin[rt][reg];
#pragma unroll
            for (int off = 1; off < 16; off <<= 1)
                v = fminf(v, __shfl_xor(v, off, 64));
            if ((lane & 15) == 0)
                atomicMin(&bmin[rt * 16 + (lane >> 4) * 4 + reg],
                          __float_as_uint(fmaxf(v, 0.f)));
        }
    __syncthreads();

    // ---- collect candidates from live accs vs block threshold ----
    float thr[2][4];
#pragma unroll
    for (int rt = 0; rt < 2; ++rt)
#pragma unroll
        for (int reg = 0; reg < 4; ++reg)
            thr[rt][reg] = __uint_as_float(
                bmin[rt * 16 + (lane >> 4) * 4 + reg]) + MARGIN;

#pragma unroll
    for (int rt = 0; rt < 2; ++rt)
#pragma unroll
        for (int ct = 0; ct < 8; ++ct)
#pragma unroll
            for (int reg = 0; reg < 4; ++reg) {
                float d2 = fmaf(-2.f, acc[rt][ct][reg], x2p[rt][reg] + c2v[ct]);
                if (d2 <= thr[rt][reg]) {
                    unsigned rloc = rt * 16 + (lane >> 4) * 4 + reg;
                    unsigned col  = (unsigned)((kt0 + ct) * 16 + (lane & 15));
                    unsigned idx = atomicAdd(&cnt, 1u);
                    if (idx < CAP) buf[idx] = (rloc << 11) | col;
                    else refine_one(x, center, c2, x2g, partial,
                                    (int)(rb + rloc), (int)col);
                }
            }
    __syncthreads();

    // ---- exact refine survivors (R1-identical chain, x from global) ----
    unsigned n = cnt; if (n > CAP) n = CAP;
    for (unsigned i = tid; i < n; i += 256) {
        unsigned e = buf[i];
        int rloc = (e >> 11) & 31, col = e & (NK - 1);
        refine_one(x, center, c2, x2g, partial, (int)(rb + rloc), col);
    }
}

// ---------------------------------------------------------------------------
// Merge: one wave per row — read final key, gather center row, write label.
// ---------------------------------------------------------------------------
__global__ __launch_bounds__(256)
void merge(const u64* __restrict__ partial,
           const float* __restrict__ center,
           float* __restrict__ out,
           float* __restrict__ label_out) {
    const long row  = (long)blockIdx.x * 4 + (threadIdx.x >> 6);
    const int  lane = threadIdx.x & 63;
    u64 b = partial[row];
    int bk = (int)(b & 0xffffffffULL);
    float2 cv = ((const float2*)(center + (long)bk * ND))[lane];
    ((float2*)(out + row * ND))[lane] = cv;
    if (lane == 0) label_out[row] = (float)bk;
}

// ---------------------------------------------------------------------------
extern "C" void kernel_launch(void* const* d_in, const int* in_sizes, int n_in,
                              void* d_out, int out_size, void* d_ws, size_t ws_size,
                              hipStream_t stream) {
    const float* x      = (const float*)d_in[0];   // [B][D]
    const float* center = (const float*)d_in[1];   // [K][D]
    float* out = (float*)d_out;

    float* out_x      = out;                        // [B*D]
    float* out_center = out + (long)NB * ND;        // [K*D]
    float* out_label  = out_center + (long)NK * ND; // [B]

    // Workspace: xbf[B*D]u16 (4MB), cbf[K*D]u16 (0.5MB), partial[B]u64,
    // c2[K]f32, x2[B]f32   (~4.8 MB)
    unsigned short* xbf = (unsigned short*)d_ws;
    unsigned short* cbf = xbf + (size_t)NB * ND;
    u64*   partial = (u64*)(cbf + (size_t)NK * ND);
    float* c2 = (float*)(partial + NB);
    float* x2 = c2 + NK;

    prep<<<5512, 256, 0, stream>>>(x, center, xbf, cbf, c2, x2, partial,
                                   out_center);
    kmeans_main<<<2048, 256, 0, stream>>>(xbf, cbf, c2, x2, x, center, partial);
    merge<<<NB / 4, 256, 0, stream>>>(partial, center, out_x, out_label);
}